// Round 13
// baseline (54.718 us; speedup 1.0000x reference)
//
#include <hip/hip_runtime.h>

// CoOccurrence via MFMA, R13: R9 structure (validated 26.2us) + two serial
// tiles per block, NO cross-phase register holding (R10/R11's rg[] prefetch
// spilled at every launch_bounds; R13 stages load->convert->LDS-write inline
// per task, R9's proven 68-VGPR pattern). Grid 784 = 8 images (XCD-pinned,
// bid&7) x 98 horizontal tile-pairs -> all blocks resident in ONE batch
// (3.06/CU at 4/CU cap), per-block setup amortized, paired tiles share halo
// columns through the same XCD's L2 (R10/R11 measured FETCH 86->15-36MB).
// Layouts (validated R7-R9):
//   Hs_t[pos][64]  fp16 XOR-swizzled, k=channel contiguous (GEMM1 A/B, norms)
//   Hs2 [ch ][160] fp16 flat-XOR swizzle, k=pos contiguous (GEMM2 B)
//   Wt  [p  ][96]  fp16 (aliases Hs_t), per-quadrant 96-col k-window (GEMM2 A)
// GEMM1: D[q,p] = sum_ch x[ch,q] x[ch,p]  (band-restricted m-tiles)
// epi1 : W[p,q] = ((D/max(|x_p||x_q|,eps))+1)/2 * sw  (0 outside 5x5 band)
// GEMM2: out[p,ch] = sum_q W[p,q] x[ch,q]  (k-windows 0,0,32,64)
// Zero-padded halo: OOB taps are 0 -> contribution exactly 0. Hs2 pos-tail
// [144,160) zeroed once per block; staging only writes [0,144) so it stays 0.

typedef _Float16 half8 __attribute__((ext_vector_type(8)));
typedef _Float16 half4 __attribute__((ext_vector_type(4)));
typedef _Float16 half2t __attribute__((ext_vector_type(2)));
typedef float f32x4 __attribute__((ext_vector_type(4)));
typedef float f32x2 __attribute__((ext_vector_type(2)));

constexpr int Cc = 64, Hc = 112, Wc = 112;
constexpr int HWc = Hc * Wc;
constexpr float EPSc = 1e-8f;
constexpr int TH = 8, TW = 8;
constexpr int WR = 12, HALO = 144;   // 12x12 halo
constexpr int ST_2 = 160;            // Hs2 row stride
constexpr int ST_W = 96;             // Wt row stride
constexpr int NTX = 14;              // 112/8

__device__ __forceinline__ int idxt(int pos, int col) {   // Hs_t swizzle
    return pos * 64 + (col ^ ((pos & 7) << 3));           // bijective: col<64
}
__device__ __forceinline__ int idx2(int row, int col) {   // Hs2 swizzle
    return (row * ST_2 + col) ^ ((row & 7) << 3);
}
__device__ __forceinline__ int idxw(int row, int col) {   // Wt swizzle
    return (row * ST_W + col) ^ ((row & 7) << 3);
}

__global__ __launch_bounds__(256, 4) void cooc_mfma(
    const float* __restrict__ x, const float* __restrict__ swg,
    float* __restrict__ out)
{
    __shared__ __align__(16) _Float16 Hs_t[HALO * 64];    // 18432 B (Wt aliases)
    __shared__ __align__(16) _Float16 Hs2[64 * ST_2];     // 20480 B
    __shared__ float nxs[HALO];
    __shared__ float sws[25];
    _Float16* const Wt = Hs_t;   // alias: Hs_t dead after GEMM1/norm/b2 reads

    const int t = threadIdx.x;
    const int wv = t >> 6, l = t & 63;
    const int lo16 = l & 15, hi4 = l >> 4;
    // 784 blocks = 8 images (one per XCD via bid&7) x 98 horizontal pairs.
    const int bid = blockIdx.x;
    const int b = bid & 7;
    const int pair = bid >> 3;             // 0..97
    const int tile0 = pair * 2;            // pairs never straddle rows (14 even)
    const int trow = tile0 / NTX;
    const int h0 = trow * TH;
    const int w00 = (tile0 - trow * NTX) * TW;
    const float* xb = x + (size_t)b * Cc * HWc;
    const half8 z8 = {0, 0, 0, 0, 0, 0, 0, 0};

    // Lane constants (tile-independent).
    const int p = wv * 16 + lo16;
    const int cpos = ((p >> 3) + 2) * WR + (p & 7) + 2;
    const int mt_lo = (3 * wv) >> 1;                 // 0,1,3,4

    // ---- once: zero Hs2 k-tail cols [144,160); load sws ----
    if (t < 128) {
        const int row = t >> 1, c8 = 144 + (t & 1) * 8;
        *(half8*)&Hs2[idx2(row, c8)] = z8;
    }
    if (t < 25) sws[t] = swg[t];

    for (int i = 0; i < 2; ++i) {
        const int w0 = w00 + i * TW;

        // ---- stage: task=(4-ch group cq, pos-pair pp); 1152 tasks;
        //      load -> convert -> LDS write inline (no held registers) ----
#pragma unroll
        for (int it = 0; it < 5; ++it) {
            const int task = t + it * 256;
            if (task < 1152) {
                const int cq = task / 72;
                const int pp = task - cq * 72;
                const int r_ = pp / 6, pc2 = (pp - r_ * 6) * 2;
                const int gh = h0 + r_ - 2, gw = w0 + pc2 - 2;   // gw even
                const bool inb = ((unsigned)gh < (unsigned)Hc) &&
                                 ((unsigned)gw < (unsigned)Wc);
                const int ch0 = cq * 4;
                const float* src = xb + (size_t)ch0 * HWc + gh * Wc + gw;
                const f32x2 z = {0.f, 0.f};
                f32x2 v0 = z, v1 = z, v2 = z, v3 = z;
                if (inb) {
                    v0 = *(const f32x2*)(src);
                    v1 = *(const f32x2*)(src + (size_t)1 * HWc);
                    v2 = *(const f32x2*)(src + (size_t)2 * HWc);
                    v3 = *(const f32x2*)(src + (size_t)3 * HWc);
                }
                const int pos0 = r_ * WR + pc2;
                const half4 hx = {(_Float16)v0.x, (_Float16)v1.x,
                                  (_Float16)v2.x, (_Float16)v3.x};
                const half4 hy = {(_Float16)v0.y, (_Float16)v1.y,
                                  (_Float16)v2.y, (_Float16)v3.y};
                *(half4*)&Hs_t[idxt(pos0, ch0)] = hx;
                *(half4*)&Hs_t[idxt(pos0 + 1, ch0)] = hy;
                const half2t p0 = {hx[0], hy[0]}, p1 = {hx[1], hy[1]};
                const half2t p2 = {hx[2], hy[2]}, p3 = {hx[3], hy[3]};
                *(half2t*)&Hs2[idx2(ch0 + 0, pos0)] = p0;
                *(half2t*)&Hs2[idx2(ch0 + 1, pos0)] = p1;
                *(half2t*)&Hs2[idx2(ch0 + 2, pos0)] = p2;
                *(half2t*)&Hs2[idx2(ch0 + 3, pos0)] = p3;
            }
        }
        __syncthreads();

        // ---- nxs[pos] = ||x(pos)|| (threads 0-143) ----
        if (t < HALO) {
            float s = 0.f;
#pragma unroll
            for (int ii = 0; ii < 8; ++ii) {
                const half8 h = *(const half8*)&Hs_t[idxt(t, ii * 8)];
#pragma unroll
                for (int j = 0; j < 8; ++j) {
                    const float f = (float)h[j];
                    s = fmaf(f, f, s);
                }
            }
            nxs[t] = sqrtf(s);
        }

        // ---- GEMM1: D = H^T*C; wave wv: centers p (n), 5 band m-tiles ----
        half8 bfr[2];
#pragma unroll
        for (int ks = 0; ks < 2; ++ks)
            bfr[ks] = *(const half8*)&Hs_t[idxt(cpos, ks * 32 + hi4 * 8)];

        f32x4 acc[5];
#pragma unroll
        for (int ii = 0; ii < 5; ++ii) acc[ii] = (f32x4){0.f, 0.f, 0.f, 0.f};
#pragma unroll
        for (int ii = 0; ii < 5; ++ii) {
            const int q0 = (mt_lo + ii) * 16 + lo16;
#pragma unroll
            for (int ks = 0; ks < 2; ++ks) {
                const half8 afr = *(const half8*)&Hs_t[idxt(q0, ks * 32 + hi4 * 8)];
                acc[ii] = __builtin_amdgcn_mfma_f32_16x16x32_f16(afr, bfr[ks], acc[ii], 0, 0, 0);
            }
        }

        // ---- GEMM2 B-frags from Hs2 (before Wt overwrites Hs_t) ----
        half8 b2[5];
#pragma unroll
        for (int ks = 0; ks < 5; ++ks)
            b2[ks] = *(const half8*)&Hs2[idx2(wv * 16 + lo16, ks * 32 + hi4 * 8)];

        __syncthreads();   // Hs_t/norm reads done; nxs visible; Wt writable

        // ---- zero Wt's unwritten 16 cols per row, then epi1 ----
        {
            const int zc = (wv == 0 || wv == 3) ? 80 : 0;
            if (hi4 < 2) *(half8*)&Wt[idxw(p, zc + hi4 * 8)] = z8;

            const float nxp = nxs[cpos];
            const int W0 = ((3 * wv) >> 2) * 32;     // 0,0,32,64
            const int prw = p >> 3, pcl = p & 7;
#pragma unroll
            for (int ii = 0; ii < 5; ++ii) {
                const int qb = (mt_lo + ii) * 16 + hi4 * 4;
                _Float16 hw[4];
#pragma unroll
                for (int r = 0; r < 4; ++r) {
                    const int q = qb + r;
                    const int qr = q / WR, qc = q - qr * WR;
                    const int ih = qr - prw, iw = qc - pcl;
                    const float sv = ((unsigned)ih <= 4u && (unsigned)iw <= 4u)
                                         ? sws[ih * 5 + iw] : 0.f;
                    const float denom = fmaxf(nxp * nxs[q], EPSc);
                    const float sim = acc[ii][r] / denom;
                    hw[r] = (_Float16)((sim + 1.f) * 0.5f * sv);
                }
                const half4 w4 = {hw[0], hw[1], hw[2], hw[3]};
                *(half4*)&Wt[idxw(p, qb - W0)] = w4;
            }
        }
        __syncthreads();   // Wt complete

        // ---- GEMM2: out[p,ch] = sum_q W[p,q] x[ch,q]; A=Wt frags, B=b2 ----
        f32x4 acc2[4];
#pragma unroll
        for (int nt = 0; nt < 4; ++nt) acc2[nt] = (f32x4){0.f, 0.f, 0.f, 0.f};
#pragma unroll
        for (int nt = 0; nt < 4; ++nt) {
            const int ksl = (3 * nt) >> 2;           // 0,0,1,2
#pragma unroll
            for (int s = 0; s < 3; ++s) {
                const half8 wtf = *(const half8*)&Wt[idxw(nt * 16 + lo16, s * 32 + hi4 * 8)];
                acc2[nt] = __builtin_amdgcn_mfma_f32_16x16x32_f16(wtf, b2[ksl + s], acc2[nt], 0, 0, 0);
            }
        }

        // ---- epi2: lane owns ch = wv*16+lo16; 4 consecutive pixels -> float4 ----
        {
            const int ch = wv * 16 + lo16;
            float* ochan = out + (size_t)b * Cc * HWc + (size_t)ch * HWc;
            const int pr_base = hi4 >> 1, pc0 = (hi4 & 1) * 4;
#pragma unroll
            for (int nt = 0; nt < 4; ++nt) {
                const int gh = h0 + 2 * nt + pr_base;
                *(f32x4*)&ochan[gh * Wc + w0 + pc0] = acc2[nt];
            }
        }

        if (i == 0) __syncthreads();   // all Wt/Hs2 reads done before restage
    }
}

extern "C" void kernel_launch(void* const* d_in, const int* in_sizes, int n_in,
                              void* d_out, int out_size, void* d_ws, size_t ws_size,
                              hipStream_t stream) {
    const float* x = (const float*)d_in[0];
    const float* sw = (const float*)d_in[1];
    float* out = (float*)d_out;
    cooc_mfma<<<dim3(8 * (NTX * NTX / 2)), dim3(256), 0, stream>>>(x, sw, out);
}

// Round 14
// 25.111 us; speedup vs baseline: 2.1791x; 2.1791x over previous
//
#include <hip/hip_runtime.h>

// CoOccurrence via MFMA, R14: R9 structure byte-for-byte (single tile/block,
// 1568 blocks, XCD swizzle via bid&7, 4 blocks/CU) with ONE change: staging
// is split into (a) issue ALL 20 global dwordx2 loads into a transient
// statically-indexed register buffer, (b) convert+write all to LDS. The
// buffer dies before acc/b2 go live (unlike R10/R11/R13's cross-phase
// prefetch, which spilled 3/3 times), so allocation stays R9-like while the
// 5 serialized L2/HBM round-trips collapse toward 1 (counted vmcnt waits).
// Layouts (validated R7-R9):
//   Hs_t[pos][64]  fp16 XOR-swizzled, k=channel contiguous (GEMM1 A/B, norms)
//   Hs2 [ch ][160] fp16 flat-XOR swizzle, k=pos contiguous (GEMM2 B)
//   Wt  [p  ][96]  fp16 (aliases Hs_t), per-quadrant 96-col k-window (GEMM2 A)
// GEMM1: D[q,p] = sum_ch x[ch,q] x[ch,p]  (band-restricted m-tiles)
// epi1 : W[p,q] = ((D/max(|x_p||x_q|,eps))+1)/2 * sw  (0 outside 5x5 band)
// GEMM2: out[p,ch] = sum_q W[p,q] x[ch,q]  (k-windows 0,0,32,64)
// Zero-padded halo: OOB taps are 0 -> contribution exactly 0 (reference
// zero-pad semantics). Hs2 pos-tail [144,160) zeroed once.

typedef _Float16 half8 __attribute__((ext_vector_type(8)));
typedef _Float16 half4 __attribute__((ext_vector_type(4)));
typedef _Float16 half2t __attribute__((ext_vector_type(2)));
typedef float f32x4 __attribute__((ext_vector_type(4)));
typedef float f32x2 __attribute__((ext_vector_type(2)));

constexpr int Cc = 64, Hc = 112, Wc = 112;
constexpr int HWc = Hc * Wc;
constexpr float EPSc = 1e-8f;
constexpr int TH = 8, TW = 8;
constexpr int WR = 12, HALO = 144;   // 12x12 halo
constexpr int ST_2 = 160;            // Hs2 row stride
constexpr int ST_W = 96;             // Wt row stride
constexpr int NTX = 14;              // 112/8

__device__ __forceinline__ int idxt(int pos, int col) {   // Hs_t swizzle
    return pos * 64 + (col ^ ((pos & 7) << 3));           // bijective: col<64
}
__device__ __forceinline__ int idx2(int row, int col) {   // Hs2 swizzle
    return (row * ST_2 + col) ^ ((row & 7) << 3);
}
__device__ __forceinline__ int idxw(int row, int col) {   // Wt swizzle
    return (row * ST_W + col) ^ ((row & 7) << 3);
}

__global__ __launch_bounds__(256, 4) void cooc_mfma(
    const float* __restrict__ x, const float* __restrict__ swg,
    float* __restrict__ out)
{
    __shared__ __align__(16) _Float16 Hs_t[HALO * 64];    // 18432 B (Wt aliases)
    __shared__ __align__(16) _Float16 Hs2[64 * ST_2];     // 20480 B
    __shared__ float nxs[HALO];
    __shared__ float sws[25];
    _Float16* const Wt = Hs_t;   // alias: Hs_t dead after GEMM1/norm/b2 reads

    const int t = threadIdx.x;
    const int wv = t >> 6, l = t & 63;
    const int lo16 = l & 15, hi4 = l >> 4;
    // XCD swizzle: 1568 = 8 images x 196 tiles; bid&7 = image (one per XCD).
    const int bid = blockIdx.x;
    const int b = bid & 7;
    const int tile = bid >> 3;
    const int th = tile / NTX, twi = tile - th * NTX;
    const int h0 = th * TH, w0 = twi * TW;
    const float* xb = x + (size_t)b * Cc * HWc;
    const half8 z8 = {0, 0, 0, 0, 0, 0, 0, 0};

    // ---- phase 0: zero Hs2 k-tail cols [144,160); load sws ----
    if (t < 128) {
        const int row = t >> 1, c8 = 144 + (t & 1) * 8;
        *(half8*)&Hs2[idx2(row, c8)] = z8;
    }
    if (t < 25) sws[t] = swg[t];

    // ---- phase 1: stage. task=(4-ch group cq, pos-pair pp); 1152 tasks.
    //      Sub-phase A: issue ALL loads (transient regs, static indices).
    //      Sub-phase B: convert + write LDS. ----
    {
        f32x2 v[5][4];
        int pos_[5], ch_[5];
#pragma unroll
        for (int it = 0; it < 5; ++it) {
            const int task = t + it * 256;
            const f32x2 z = {0.f, 0.f};
            v[it][0] = z; v[it][1] = z; v[it][2] = z; v[it][3] = z;
            pos_[it] = -1; ch_[it] = 0;
            if (task < 1152) {
                const int cq = task / 72;
                const int pp = task - cq * 72;
                const int r_ = pp / 6, pc2 = (pp - r_ * 6) * 2;
                const int gh = h0 + r_ - 2, gw = w0 + pc2 - 2;   // gw even
                const bool inb = ((unsigned)gh < (unsigned)Hc) &&
                                 ((unsigned)gw < (unsigned)Wc);
                pos_[it] = r_ * WR + pc2;
                ch_[it] = cq * 4;
                if (inb) {
                    const float* src = xb + (size_t)(cq * 4) * HWc + gh * Wc + gw;
                    v[it][0] = *(const f32x2*)(src);
                    v[it][1] = *(const f32x2*)(src + (size_t)1 * HWc);
                    v[it][2] = *(const f32x2*)(src + (size_t)2 * HWc);
                    v[it][3] = *(const f32x2*)(src + (size_t)3 * HWc);
                }
            }
        }
#pragma unroll
        for (int it = 0; it < 5; ++it) {
            if (pos_[it] >= 0) {
                const int pos0 = pos_[it], ch0 = ch_[it];
                const f32x2 v0 = v[it][0], v1 = v[it][1];
                const f32x2 v2 = v[it][2], v3 = v[it][3];
                const half4 hx = {(_Float16)v0.x, (_Float16)v1.x,
                                  (_Float16)v2.x, (_Float16)v3.x};
                const half4 hy = {(_Float16)v0.y, (_Float16)v1.y,
                                  (_Float16)v2.y, (_Float16)v3.y};
                *(half4*)&Hs_t[idxt(pos0, ch0)] = hx;
                *(half4*)&Hs_t[idxt(pos0 + 1, ch0)] = hy;
                const half2t p0 = {hx[0], hy[0]}, p1 = {hx[1], hy[1]};
                const half2t p2 = {hx[2], hy[2]}, p3 = {hx[3], hy[3]};
                *(half2t*)&Hs2[idx2(ch0 + 0, pos0)] = p0;
                *(half2t*)&Hs2[idx2(ch0 + 1, pos0)] = p1;
                *(half2t*)&Hs2[idx2(ch0 + 2, pos0)] = p2;
                *(half2t*)&Hs2[idx2(ch0 + 3, pos0)] = p3;
            }
        }
    }
    __syncthreads();

    // ---- nxs[pos] = ||x(pos)|| (threads 0-143; waves 2-3 run ahead) ----
    if (t < HALO) {
        float s = 0.f;
#pragma unroll
        for (int i = 0; i < 8; ++i) {
            const half8 h = *(const half8*)&Hs_t[idxt(t, i * 8)];
#pragma unroll
            for (int j = 0; j < 8; ++j) {
                const float f = (float)h[j];
                s = fmaf(f, f, s);
            }
        }
        nxs[t] = sqrtf(s);
    }

    // ---- GEMM1: D = H^T*C; wave wv: centers p (n), 5 band m-tiles ----
    const int p = wv * 16 + lo16;
    const int cpos = ((p >> 3) + 2) * WR + (p & 7) + 2;
    half8 bfr[2];
#pragma unroll
    for (int ks = 0; ks < 2; ++ks)
        bfr[ks] = *(const half8*)&Hs_t[idxt(cpos, ks * 32 + hi4 * 8)];

    const int mt_lo = (3 * wv) >> 1;                 // 0,1,3,4
    f32x4 acc[5];
#pragma unroll
    for (int i = 0; i < 5; ++i) acc[i] = (f32x4){0.f, 0.f, 0.f, 0.f};
#pragma unroll
    for (int i = 0; i < 5; ++i) {
        const int q0 = (mt_lo + i) * 16 + lo16;
#pragma unroll
        for (int ks = 0; ks < 2; ++ks) {
            const half8 afr = *(const half8*)&Hs_t[idxt(q0, ks * 32 + hi4 * 8)];
            acc[i] = __builtin_amdgcn_mfma_f32_16x16x32_f16(afr, bfr[ks], acc[i], 0, 0, 0);
        }
    }

    // ---- GEMM2 B-frags from Hs2 (before Wt overwrites Hs_t) ----
    half8 b2[5];
#pragma unroll
    for (int ks = 0; ks < 5; ++ks)
        b2[ks] = *(const half8*)&Hs2[idx2(wv * 16 + lo16, ks * 32 + hi4 * 8)];

    __syncthreads();   // Hs_t/norm reads done; nxs visible; Wt writable

    // ---- zero Wt's unwritten 16 cols per row, then epi1 ----
    {
        const int zc = (wv == 0 || wv == 3) ? 80 : 0;
        if (hi4 < 2) *(half8*)&Wt[idxw(p, zc + hi4 * 8)] = z8;

        const float nxp = nxs[cpos];
        const int W0 = ((3 * wv) >> 2) * 32;         // 0,0,32,64
        const int prw = p >> 3, pcl = p & 7;
#pragma unroll
        for (int i = 0; i < 5; ++i) {
            const int qb = (mt_lo + i) * 16 + hi4 * 4;
            _Float16 hw[4];
#pragma unroll
            for (int r = 0; r < 4; ++r) {
                const int q = qb + r;
                const int qr = q / WR, qc = q - qr * WR;
                const int ih = qr - prw, iw = qc - pcl;
                const float sv = ((unsigned)ih <= 4u && (unsigned)iw <= 4u)
                                     ? sws[ih * 5 + iw] : 0.f;
                const float denom = fmaxf(nxp * nxs[q], EPSc);
                const float sim = acc[i][r] / denom;
                hw[r] = (_Float16)((sim + 1.f) * 0.5f * sv);
            }
            const half4 w4 = {hw[0], hw[1], hw[2], hw[3]};
            *(half4*)&Wt[idxw(p, qb - W0)] = w4;
        }
    }
    __syncthreads();   // Wt complete

    // ---- GEMM2: out[p,ch] = sum_q W[p,q] x[ch,q]; A=Wt frags, B=b2 ----
    f32x4 acc2[4];
#pragma unroll
    for (int nt = 0; nt < 4; ++nt) acc2[nt] = (f32x4){0.f, 0.f, 0.f, 0.f};
#pragma unroll
    for (int nt = 0; nt < 4; ++nt) {
        const int ksl = (3 * nt) >> 2;               // 0,0,1,2
#pragma unroll
        for (int s = 0; s < 3; ++s) {
            const half8 wtf = *(const half8*)&Wt[idxw(nt * 16 + lo16, s * 32 + hi4 * 8)];
            acc2[nt] = __builtin_amdgcn_mfma_f32_16x16x32_f16(wtf, b2[ksl + s], acc2[nt], 0, 0, 0);
        }
    }

    // ---- epi2: lane owns ch = wv*16+lo16; 4 consecutive pixels -> float4 ----
    {
        const int ch = wv * 16 + lo16;
        float* ochan = out + (size_t)b * Cc * HWc + (size_t)ch * HWc;
        const int pr_base = hi4 >> 1, pc0 = (hi4 & 1) * 4;
#pragma unroll
        for (int nt = 0; nt < 4; ++nt) {
            const int gh = h0 + 2 * nt + pr_base;
            *(f32x4*)&ochan[gh * Wc + w0 + pc0] = acc2[nt];
        }
    }
}

extern "C" void kernel_launch(void* const* d_in, const int* in_sizes, int n_in,
                              void* d_out, int out_size, void* d_ws, size_t ws_size,
                              hipStream_t stream) {
    const float* x = (const float*)d_in[0];
    const float* sw = (const float*)d_in[1];
    float* out = (float*)d_out;
    cooc_mfma<<<dim3(8 * NTX * NTX), dim3(256), 0, stream>>>(x, sw, out);
}

// Round 15
// 24.353 us; speedup vs baseline: 2.2468x; 1.0311x over previous
//
#include <hip/hip_runtime.h>

// CoOccurrence via MFMA, R15: R14 structure byte-for-byte with the epilogue
// math leaned out: norms stored SQUARED (no sqrt in phase 1b), and epi1 uses
//   sim = dot * rsqrt(max(n2p*n2q, eps^2))
// (monotone-equivalent to dot / max(sqrt(n2p)*sqrt(n2q), eps)), replacing 25
// IEEE f32 divides/lane (div_scale/fmas/fixup, ~300-500cy serial) with 25
// v_rsq_f32 + muls. Edge semantics exact: OOB tap -> dot=0 -> sim=0; center
// tap -> n2p*rsqrt(n2p^2)=1.
// Layouts (validated R7-R14):
//   Hs_t[pos][64]  fp16 XOR-swizzled, k=channel contiguous (GEMM1 A/B, norms)
//   Hs2 [ch ][160] fp16 flat-XOR swizzle, k=pos contiguous (GEMM2 B)
//   Wt  [p  ][96]  fp16 (aliases Hs_t), per-quadrant 96-col k-window (GEMM2 A)
// GEMM1: D[q,p] = sum_ch x[ch,q] x[ch,p]  (band-restricted m-tiles)
// epi1 : W[p,q] = ((sim+1)/2) * sw  (0 outside 5x5 band)
// GEMM2: out[p,ch] = sum_q W[p,q] x[ch,q]  (k-windows 0,0,32,64)
// Zero-padded halo: OOB taps are 0 -> contribution exactly 0. Staging: issue
// all 20 dwordx2 loads into a transient statically-indexed buffer (dead
// before acc/b2 live -> no spill; R14 verified WRITE=25088KB), then convert
// + write LDS.

typedef _Float16 half8 __attribute__((ext_vector_type(8)));
typedef _Float16 half4 __attribute__((ext_vector_type(4)));
typedef _Float16 half2t __attribute__((ext_vector_type(2)));
typedef float f32x4 __attribute__((ext_vector_type(4)));
typedef float f32x2 __attribute__((ext_vector_type(2)));

constexpr int Cc = 64, Hc = 112, Wc = 112;
constexpr int HWc = Hc * Wc;
constexpr int TH = 8, TW = 8;
constexpr int WR = 12, HALO = 144;   // 12x12 halo
constexpr int ST_2 = 160;            // Hs2 row stride
constexpr int ST_W = 96;             // Wt row stride
constexpr int NTX = 14;              // 112/8

__device__ __forceinline__ int idxt(int pos, int col) {   // Hs_t swizzle
    return pos * 64 + (col ^ ((pos & 7) << 3));           // bijective: col<64
}
__device__ __forceinline__ int idx2(int row, int col) {   // Hs2 swizzle
    return (row * ST_2 + col) ^ ((row & 7) << 3);
}
__device__ __forceinline__ int idxw(int row, int col) {   // Wt swizzle
    return (row * ST_W + col) ^ ((row & 7) << 3);
}

__global__ __launch_bounds__(256, 4) void cooc_mfma(
    const float* __restrict__ x, const float* __restrict__ swg,
    float* __restrict__ out)
{
    __shared__ __align__(16) _Float16 Hs_t[HALO * 64];    // 18432 B (Wt aliases)
    __shared__ __align__(16) _Float16 Hs2[64 * ST_2];     // 20480 B
    __shared__ float n2s[HALO];                           // squared norms
    __shared__ float sws[25];
    _Float16* const Wt = Hs_t;   // alias: Hs_t dead after GEMM1/norm/b2 reads

    const int t = threadIdx.x;
    const int wv = t >> 6, l = t & 63;
    const int lo16 = l & 15, hi4 = l >> 4;
    // XCD swizzle: 1568 = 8 images x 196 tiles; bid&7 = image (one per XCD).
    const int bid = blockIdx.x;
    const int b = bid & 7;
    const int tile = bid >> 3;
    const int th = tile / NTX, twi = tile - th * NTX;
    const int h0 = th * TH, w0 = twi * TW;
    const float* xb = x + (size_t)b * Cc * HWc;
    const half8 z8 = {0, 0, 0, 0, 0, 0, 0, 0};

    // ---- phase 0: zero Hs2 k-tail cols [144,160); load sws ----
    if (t < 128) {
        const int row = t >> 1, c8 = 144 + (t & 1) * 8;
        *(half8*)&Hs2[idx2(row, c8)] = z8;
    }
    if (t < 25) sws[t] = swg[t];

    // ---- phase 1: stage. task=(4-ch group cq, pos-pair pp); 1152 tasks.
    //      Sub-phase A: issue ALL loads (transient regs, static indices).
    //      Sub-phase B: convert + write LDS. ----
    {
        f32x2 v[5][4];
        int pos_[5], ch_[5];
#pragma unroll
        for (int it = 0; it < 5; ++it) {
            const int task = t + it * 256;
            const f32x2 z = {0.f, 0.f};
            v[it][0] = z; v[it][1] = z; v[it][2] = z; v[it][3] = z;
            pos_[it] = -1; ch_[it] = 0;
            if (task < 1152) {
                const int cq = task / 72;
                const int pp = task - cq * 72;
                const int r_ = pp / 6, pc2 = (pp - r_ * 6) * 2;
                const int gh = h0 + r_ - 2, gw = w0 + pc2 - 2;   // gw even
                const bool inb = ((unsigned)gh < (unsigned)Hc) &&
                                 ((unsigned)gw < (unsigned)Wc);
                pos_[it] = r_ * WR + pc2;
                ch_[it] = cq * 4;
                if (inb) {
                    const float* src = xb + (size_t)(cq * 4) * HWc + gh * Wc + gw;
                    v[it][0] = *(const f32x2*)(src);
                    v[it][1] = *(const f32x2*)(src + (size_t)1 * HWc);
                    v[it][2] = *(const f32x2*)(src + (size_t)2 * HWc);
                    v[it][3] = *(const f32x2*)(src + (size_t)3 * HWc);
                }
            }
        }
#pragma unroll
        for (int it = 0; it < 5; ++it) {
            if (pos_[it] >= 0) {
                const int pos0 = pos_[it], ch0 = ch_[it];
                const f32x2 v0 = v[it][0], v1 = v[it][1];
                const f32x2 v2 = v[it][2], v3 = v[it][3];
                const half4 hx = {(_Float16)v0.x, (_Float16)v1.x,
                                  (_Float16)v2.x, (_Float16)v3.x};
                const half4 hy = {(_Float16)v0.y, (_Float16)v1.y,
                                  (_Float16)v2.y, (_Float16)v3.y};
                *(half4*)&Hs_t[idxt(pos0, ch0)] = hx;
                *(half4*)&Hs_t[idxt(pos0 + 1, ch0)] = hy;
                const half2t p0 = {hx[0], hy[0]}, p1 = {hx[1], hy[1]};
                const half2t p2 = {hx[2], hy[2]}, p3 = {hx[3], hy[3]};
                *(half2t*)&Hs2[idx2(ch0 + 0, pos0)] = p0;
                *(half2t*)&Hs2[idx2(ch0 + 1, pos0)] = p1;
                *(half2t*)&Hs2[idx2(ch0 + 2, pos0)] = p2;
                *(half2t*)&Hs2[idx2(ch0 + 3, pos0)] = p3;
            }
        }
    }
    __syncthreads();

    // ---- n2s[pos] = ||x(pos)||^2 (threads 0-143; waves 2-3 run ahead) ----
    if (t < HALO) {
        float s = 0.f;
#pragma unroll
        for (int i = 0; i < 8; ++i) {
            const half8 h = *(const half8*)&Hs_t[idxt(t, i * 8)];
#pragma unroll
            for (int j = 0; j < 8; ++j) {
                const float f = (float)h[j];
                s = fmaf(f, f, s);
            }
        }
        n2s[t] = s;
    }

    // ---- GEMM1: D = H^T*C; wave wv: centers p (n), 5 band m-tiles ----
    const int p = wv * 16 + lo16;
    const int cpos = ((p >> 3) + 2) * WR + (p & 7) + 2;
    half8 bfr[2];
#pragma unroll
    for (int ks = 0; ks < 2; ++ks)
        bfr[ks] = *(const half8*)&Hs_t[idxt(cpos, ks * 32 + hi4 * 8)];

    const int mt_lo = (3 * wv) >> 1;                 // 0,1,3,4
    f32x4 acc[5];
#pragma unroll
    for (int i = 0; i < 5; ++i) acc[i] = (f32x4){0.f, 0.f, 0.f, 0.f};
#pragma unroll
    for (int i = 0; i < 5; ++i) {
        const int q0 = (mt_lo + i) * 16 + lo16;
#pragma unroll
        for (int ks = 0; ks < 2; ++ks) {
            const half8 afr = *(const half8*)&Hs_t[idxt(q0, ks * 32 + hi4 * 8)];
            acc[i] = __builtin_amdgcn_mfma_f32_16x16x32_f16(afr, bfr[ks], acc[i], 0, 0, 0);
        }
    }

    // ---- GEMM2 B-frags from Hs2 (before Wt overwrites Hs_t) ----
    half8 b2[5];
#pragma unroll
    for (int ks = 0; ks < 5; ++ks)
        b2[ks] = *(const half8*)&Hs2[idx2(wv * 16 + lo16, ks * 32 + hi4 * 8)];

    __syncthreads();   // Hs_t/norm reads done; n2s visible; Wt writable

    // ---- zero Wt's unwritten 16 cols per row, then epi1 ----
    {
        const int zc = (wv == 0 || wv == 3) ? 80 : 0;
        if (hi4 < 2) *(half8*)&Wt[idxw(p, zc + hi4 * 8)] = z8;

        const float n2p = n2s[cpos];
        const int W0 = ((3 * wv) >> 2) * 32;         // 0,0,32,64
        const int prw = p >> 3, pcl = p & 7;
#pragma unroll
        for (int i = 0; i < 5; ++i) {
            const int qb = (mt_lo + i) * 16 + hi4 * 4;
            _Float16 hw[4];
#pragma unroll
            for (int r = 0; r < 4; ++r) {
                const int q = qb + r;
                const int qr = q / WR, qc = q - qr * WR;
                const int ih = qr - prw, iw = qc - pcl;
                const float sv = ((unsigned)ih <= 4u && (unsigned)iw <= 4u)
                                     ? sws[ih * 5 + iw] : 0.f;
                // sim = dot * rsqrt(max(n2p*n2q, eps^2))
                //     == dot / max(sqrt(n2p*n2q), eps)   (monotone equiv)
                const float prod = n2p * n2s[q];
                const float inv = __builtin_amdgcn_rsqf(fmaxf(prod, 1e-16f));
                const float sim = acc[i][r] * inv;
                hw[r] = (_Float16)((sim + 1.f) * 0.5f * sv);
            }
            const half4 w4 = {hw[0], hw[1], hw[2], hw[3]};
            *(half4*)&Wt[idxw(p, qb - W0)] = w4;
        }
    }
    __syncthreads();   // Wt complete

    // ---- GEMM2: out[p,ch] = sum_q W[p,q] x[ch,q]; A=Wt frags, B=b2 ----
    f32x4 acc2[4];
#pragma unroll
    for (int nt = 0; nt < 4; ++nt) acc2[nt] = (f32x4){0.f, 0.f, 0.f, 0.f};
#pragma unroll
    for (int nt = 0; nt < 4; ++nt) {
        const int ksl = (3 * nt) >> 2;               // 0,0,1,2
#pragma unroll
        for (int s = 0; s < 3; ++s) {
            const half8 wtf = *(const half8*)&Wt[idxw(nt * 16 + lo16, s * 32 + hi4 * 8)];
            acc2[nt] = __builtin_amdgcn_mfma_f32_16x16x32_f16(wtf, b2[ksl + s], acc2[nt], 0, 0, 0);
        }
    }

    // ---- epi2: lane owns ch = wv*16+lo16; 4 consecutive pixels -> float4 ----
    {
        const int ch = wv * 16 + lo16;
        float* ochan = out + (size_t)b * Cc * HWc + (size_t)ch * HWc;
        const int pr_base = hi4 >> 1, pc0 = (hi4 & 1) * 4;
#pragma unroll
        for (int nt = 0; nt < 4; ++nt) {
            const int gh = h0 + 2 * nt + pr_base;
            *(f32x4*)&ochan[gh * Wc + w0 + pc0] = acc2[nt];
        }
    }
}

extern "C" void kernel_launch(void* const* d_in, const int* in_sizes, int n_in,
                              void* d_out, int out_size, void* d_ws, size_t ws_size,
                              hipStream_t stream) {
    const float* x = (const float*)d_in[0];
    const float* sw = (const float*)d_in[1];
    float* out = (float*)d_out;
    cooc_mfma<<<dim3(8 * NTX * NTX), dim3(256), 0, stream>>>(x, sw, out);
}